// Round 3
// baseline (105.182 us; speedup 1.0000x reference)
//
#include <hip/hip_runtime.h>

// Problem constants (from reference): B=32, S=3, T=1000, F=257
#define BATCH   32
#define NSRC    3
#define TF      257000               // T*F
#define N4      (TF / 4)             // 64250 float4 groups per (b,s) slice
#define CHUNKS  32                   // blocks per batch element -> 1024 blocks
#define THREADS 256
#define STRIDE  (CHUNKS * THREADS)   // 8192
// start in [0,8192); start + 6*8192 <= 57343 < 64250  => 7 guaranteed iters,
// 8th iteration (start + 7*8192) is conditional.

__device__ __forceinline__ void load6(float4 dst[6],
                                      const float4* __restrict__ const pr[3],
                                      const float4* __restrict__ const tg[3],
                                      int i)
{
#pragma unroll
    for (int s = 0; s < NSRC; ++s) { dst[s] = pr[s][i]; dst[3 + s] = tg[s][i]; }
}

__device__ __forceinline__ void acc6(float acc[9], const float4 v[6])
{
#pragma unroll
    for (int j = 0; j < NSRC; ++j)
#pragma unroll
        for (int k = 0; k < NSRC; ++k) {
            acc[j * 3 + k] += fabsf(v[j].x - v[3 + k].x)
                            + fabsf(v[j].y - v[3 + k].y)
                            + fabsf(v[j].z - v[3 + k].z)
                            + fabsf(v[j].w - v[3 + k].w);
        }
}

// Kernel 1: per-block pairwise partial sums, double-buffered streaming.
// partial[block*9 + j*3 + k] = block's sum of |pred[b,j]-tgt[b,k]|
__global__ __launch_bounds__(THREADS, 4) void pairwise_kernel(
    const float* __restrict__ pred,
    const float* __restrict__ tgt,
    float* __restrict__ partial)
{
    const int b     = blockIdx.x >> 5;    // / CHUNKS
    const int chunk = blockIdx.x & 31;    // % CHUNKS

    const float4* __restrict__ pr[NSRC];
    const float4* __restrict__ tg[NSRC];
#pragma unroll
    for (int s = 0; s < NSRC; ++s) {
        pr[s] = reinterpret_cast<const float4*>(pred + (size_t)(b * NSRC + s) * TF);
        tg[s] = reinterpret_cast<const float4*>(tgt  + (size_t)(b * NSRC + s) * TF);
    }

    const int start = chunk * THREADS + threadIdx.x;   // [0, 8192)

    float acc[9];
#pragma unroll
    for (int p = 0; p < 9; ++p) acc[p] = 0.0f;

    float4 bufA[6], bufB[6];

    // Ping-pong pipeline over the 7 guaranteed iterations: prefetch the next
    // 6 float4 while accumulating the current 6. All indices compile-time.
    load6(bufA, pr, tg, start);
#pragma unroll
    for (int u = 0; u < 3; ++u) {
        load6(bufB, pr, tg, start + (2 * u + 1) * STRIDE);
        acc6(acc, bufA);
        load6(bufA, pr, tg, start + (2 * u + 2) * STRIDE);
        acc6(acc, bufB);
    }
    // 7th guaranteed iteration (bufA), with conditional 8th prefetched.
    const int i7 = start + 7 * STRIDE;
    const bool has7 = (i7 < N4);
    if (has7) load6(bufB, pr, tg, i7);
    acc6(acc, bufA);
    if (has7) acc6(acc, bufB);

    // Wave shuffle-reduce, cross-wave LDS reduce, one 9-float block store.
    __shared__ float red[THREADS / 64][9];
    const int wave = threadIdx.x >> 6;
    const int lane = threadIdx.x & 63;

#pragma unroll
    for (int p = 0; p < 9; ++p) {
        float v = acc[p];
#pragma unroll
        for (int off = 32; off > 0; off >>= 1) v += __shfl_down(v, off);
        if (lane == 0) red[wave][p] = v;
    }
    __syncthreads();

    if (threadIdx.x < 9) {
        float v = red[0][threadIdx.x] + red[1][threadIdx.x]
                + red[2][threadIdx.x] + red[3][threadIdx.x];
        partial[(size_t)blockIdx.x * 9 + threadIdx.x] = v;
    }
}

// Kernel 2: reduce the 1024x9 partials, per-batch 6-perm argmin, mean.
// out[0] = mean_b min_loss[b]; out[1 + b*3 + s] = (float)best_perm[b][s]
__global__ __launch_bounds__(320) void finalize_kernel(
    const float* __restrict__ partial,
    float* __restrict__ out)
{
    __shared__ float m[BATCH][9];
    const int g = threadIdx.x;

    if (g < BATCH * 9) {
        const int b = g / 9;
        const int p = g % 9;
        float s = 0.0f;
#pragma unroll 8
        for (int c = 0; c < CHUNKS; ++c)
            s += partial[(size_t)(b * CHUNKS + c) * 9 + p];
        m[b][p] = s * (1.0f / (float)TF);
    }
    __syncthreads();

    if (threadIdx.x < 64) {
        float minv = 0.0f;
        if (threadIdx.x < BATCH) {
            const int b = threadIdx.x;
            const int perms[6][3] = {
                {0,1,2},{0,2,1},{1,0,2},{1,2,0},{2,0,1},{2,1,0}
            };
            float best = 3.402823e38f;
            int   bi   = 0;
#pragma unroll
            for (int p = 0; p < 6; ++p) {
                float l = (m[b][perms[p][0] * 3 + 0]
                         + m[b][perms[p][1] * 3 + 1]
                         + m[b][perms[p][2] * 3 + 2]) * (1.0f / 3.0f);
                if (l < best) { best = l; bi = p; }   // first-occurrence argmin
            }
            out[1 + b * 3 + 0] = (float)perms[bi][0];
            out[1 + b * 3 + 1] = (float)perms[bi][1];
            out[1 + b * 3 + 2] = (float)perms[bi][2];
            minv = best;
        }
#pragma unroll
        for (int off = 32; off > 0; off >>= 1) minv += __shfl_down(minv, off);
        if (threadIdx.x == 0) out[0] = minv * (1.0f / (float)BATCH);
    }
}

extern "C" void kernel_launch(void* const* d_in, const int* in_sizes, int n_in,
                              void* d_out, int out_size, void* d_ws, size_t ws_size,
                              hipStream_t stream)
{
    const float* pred = (const float*)d_in[0];
    const float* tgt  = (const float*)d_in[1];
    float* out     = (float*)d_out;
    float* partial = (float*)d_ws;   // 1024 * 9 floats, fully rewritten
                                     // every call (no zeroing needed)

    pairwise_kernel<<<BATCH * CHUNKS, THREADS, 0, stream>>>(pred, tgt, partial);
    finalize_kernel<<<1, 320, 0, stream>>>(partial, out);
}

// Round 4
// 104.752 us; speedup vs baseline: 1.0041x; 1.0041x over previous
//
#include <hip/hip_runtime.h>

// Problem constants (from reference): B=32, S=3, T=1000, F=257
#define BATCH   32
#define NSRC    3
#define TF      257000               // T*F
#define N4      (TF / 4)             // 64250 float4 groups per (b,s) slice
#define CHUNKS  64                   // blocks per batch element -> 2048 blocks
#define THREADS 256
#define STRIDE  (CHUNKS * THREADS)   // 16384
#define NBLOCKS (BATCH * CHUNKS)     // 2048
#define PARTIAL_FLOATS (NBLOCKS * 9) // 18432 floats = 73728 B
#define COUNTER_OFF    ((PARTIAL_FLOATS * 4 + 127) & ~127)  // 73856, own line

// ---------------------------------------------------------------------------
// Shared finalize body: reduce partial[2048][9] -> per-batch 3x3 means ->
// 6-perm argmin -> out[0]=mean(min), out[1+b*3+s]=best perm. 256 threads.
// ---------------------------------------------------------------------------
__device__ __forceinline__ void finalize_body(const float* __restrict__ partial,
                                              float* __restrict__ out)
{
    __shared__ float red2[BATCH][8][9];        // 9216 B
    const int t = threadIdx.x;                 // 0..255
    const int b = t >> 3;                      // 0..31
    const int g = t & 7;                       // 0..7 (8 chunks of 8 blocks)

    float s[9];
#pragma unroll
    for (int p = 0; p < 9; ++p) s[p] = 0.0f;

    const float* base = partial + (size_t)(b * CHUNKS + g * 8) * 9;
#pragma unroll
    for (int c = 0; c < 8; ++c)
#pragma unroll
        for (int p = 0; p < 9; ++p) s[p] += base[c * 9 + p];

#pragma unroll
    for (int p = 0; p < 9; ++p) red2[b][g][p] = s[p];
    __syncthreads();

    if (t < BATCH) {
        const int bb = t;
        float m[9];
#pragma unroll
        for (int p = 0; p < 9; ++p) {
            float v = 0.0f;
#pragma unroll
            for (int gg = 0; gg < 8; ++gg) v += red2[bb][gg][p];
            m[p] = v * (1.0f / (float)TF);
        }

        const int perms[6][3] = {
            {0,1,2},{0,2,1},{1,0,2},{1,2,0},{2,0,1},{2,1,0}
        };
        float best = 3.402823e38f;
        int   bi   = 0;
#pragma unroll
        for (int p = 0; p < 6; ++p) {
            float l = (m[perms[p][0] * 3 + 0]
                     + m[perms[p][1] * 3 + 1]
                     + m[perms[p][2] * 3 + 2]) * (1.0f / 3.0f);
            if (l < best) { best = l; bi = p; }   // first-occurrence argmin
        }
        out[1 + bb * 3 + 0] = (float)perms[bi][0];
        out[1 + bb * 3 + 1] = (float)perms[bi][1];
        out[1 + bb * 3 + 2] = (float)perms[bi][2];

        // mean of best over 32 lanes (all within wave 0, lanes 0..31)
        float minv = best;
#pragma unroll
        for (int off = 16; off > 0; off >>= 1) minv += __shfl_down(minv, off);
        if (t == 0) out[0] = minv * (1.0f / (float)BATCH);
    }
}

// ---------------------------------------------------------------------------
// Kernel 1: per-block pairwise partial sums (exact R2 streaming body —
// proven no-spill, VGPR≈52, fabric-bound). Optionally fused finalize:
// last block (device-scope atomic counter) reduces partials and writes out.
// ---------------------------------------------------------------------------
__global__ __launch_bounds__(THREADS) void pairwise_kernel(
    const float* __restrict__ pred,
    const float* __restrict__ tgt,
    float* __restrict__ partial,
    int*  counter,                    // nullptr -> no fused finalize
    float* __restrict__ out)
{
    const int b     = blockIdx.x >> 6;    // / CHUNKS
    const int chunk = blockIdx.x & 63;    // % CHUNKS

    const float4* __restrict__ pr[NSRC];
    const float4* __restrict__ tg[NSRC];
#pragma unroll
    for (int s = 0; s < NSRC; ++s) {
        pr[s] = reinterpret_cast<const float4*>(pred + (size_t)(b * NSRC + s) * TF);
        tg[s] = reinterpret_cast<const float4*>(tgt  + (size_t)(b * NSRC + s) * TF);
    }

    const int start = chunk * THREADS + threadIdx.x;   // [0, 16384)

    float acc[NSRC][NSRC];
#pragma unroll
    for (int j = 0; j < NSRC; ++j)
#pragma unroll
        for (int k = 0; k < NSRC; ++k) acc[j][k] = 0.0f;

    // 3 guaranteed strided iterations: issue all 18 loads up-front (MLP),
    // then consume. start + 2*16384 = max 49151 < 64250 always.
    float4 A[3][NSRC], T[3][NSRC];
#pragma unroll
    for (int u = 0; u < 3; ++u) {
        const int i = start + u * STRIDE;
#pragma unroll
        for (int s = 0; s < NSRC; ++s) { A[u][s] = pr[s][i]; T[u][s] = tg[s][i]; }
    }
#pragma unroll
    for (int u = 0; u < 3; ++u) {
#pragma unroll
        for (int j = 0; j < NSRC; ++j)
#pragma unroll
            for (int k = 0; k < NSRC; ++k) {
                acc[j][k] += fabsf(A[u][j].x - T[u][k].x)
                           + fabsf(A[u][j].y - T[u][k].y)
                           + fabsf(A[u][j].z - T[u][k].z)
                           + fabsf(A[u][j].w - T[u][k].w);
            }
    }

    // Conditional 4th iteration (start < 64250 - 49152 = 15098).
    const int i3 = start + 3 * STRIDE;
    if (i3 < N4) {
        float4 a[NSRC], t[NSRC];
#pragma unroll
        for (int s = 0; s < NSRC; ++s) { a[s] = pr[s][i3]; t[s] = tg[s][i3]; }
#pragma unroll
        for (int j = 0; j < NSRC; ++j)
#pragma unroll
            for (int k = 0; k < NSRC; ++k) {
                acc[j][k] += fabsf(a[j].x - t[k].x)
                           + fabsf(a[j].y - t[k].y)
                           + fabsf(a[j].z - t[k].z)
                           + fabsf(a[j].w - t[k].w);
            }
    }

    // Wave shuffle-reduce, cross-wave LDS reduce, one 9-float block store.
    __shared__ float red[THREADS / 64][9];
    __shared__ int   is_last;
    const int wave = threadIdx.x >> 6;
    const int lane = threadIdx.x & 63;

#pragma unroll
    for (int j = 0; j < NSRC; ++j)
#pragma unroll
        for (int k = 0; k < NSRC; ++k) {
            float v = acc[j][k];
#pragma unroll
            for (int off = 32; off > 0; off >>= 1) v += __shfl_down(v, off);
            if (lane == 0) red[wave][j * 3 + k] = v;
        }
    __syncthreads();

    if (threadIdx.x < 9) {
        float v = red[0][threadIdx.x] + red[1][threadIdx.x]
                + red[2][threadIdx.x] + red[3][threadIdx.x];
        partial[(size_t)blockIdx.x * 9 + threadIdx.x] = v;
    }

    if (counter) {
        // threadfence-reduction pattern: last block to arrive finalizes.
        __syncthreads();                       // partial store done block-wide
        if (threadIdx.x == 0) {
            __threadfence();                   // release: flush partials (L2 wb)
            const int old = atomicAdd(counter, 1);   // device-scope RMW
            is_last = (old == (int)gridDim.x - 1);
        }
        __syncthreads();
        if (is_last) {
            __threadfence();                   // acquire: invalidate stale L2
            finalize_body(partial, out);
        }
    }
}

// Fallback standalone finalize (used only if ws is too small for counter).
__global__ __launch_bounds__(THREADS) void finalize_kernel(
    const float* __restrict__ partial,
    float* __restrict__ out)
{
    finalize_body(partial, out);
}

extern "C" void kernel_launch(void* const* d_in, const int* in_sizes, int n_in,
                              void* d_out, int out_size, void* d_ws, size_t ws_size,
                              hipStream_t stream)
{
    const float* pred = (const float*)d_in[0];
    const float* tgt  = (const float*)d_in[1];
    float* out     = (float*)d_out;
    float* partial = (float*)d_ws;   // [2048][9] floats, fully rewritten

    if (ws_size >= (size_t)COUNTER_OFF + 128) {
        int* counter = (int*)((char*)d_ws + COUNTER_OFF);
        hipMemsetAsync(counter, 0, sizeof(int), stream);   // reset each call
        pairwise_kernel<<<NBLOCKS, THREADS, 0, stream>>>(pred, tgt, partial,
                                                         counter, out);
    } else {
        pairwise_kernel<<<NBLOCKS, THREADS, 0, stream>>>(pred, tgt, partial,
                                                         nullptr, nullptr);
        finalize_kernel<<<1, THREADS, 0, stream>>>(partial, out);
    }
}

// Round 5
// 43.150 us; speedup vs baseline: 2.4376x; 2.4276x over previous
//
#include <hip/hip_runtime.h>

// Problem constants (from reference): B=32, S=3, T=1000, F=257
#define BATCH   32
#define NSRC    3
#define TF      257000               // T*F
#define N4      (TF / 4)             // 64250 float4 groups per (b,s) slice
#define CHUNKS  64                   // blocks per batch element -> 2048 blocks
#define THREADS 256
#define STRIDE  (CHUNKS * THREADS)   // 16384

typedef float f4 __attribute__((ext_vector_type(4)));

// Kernel 1: per-block pairwise partial sums (R2 streaming body — proven
// no-spill, VGPR~52). Cache partition: pred via NONTEMPORAL loads (don't
// allocate in L3), tgt via cached loads -> tgt's 98.7 MB stays ~resident in
// the 256 MB Infinity Cache across graph replays; pred streams pure HBM.
__global__ __launch_bounds__(THREADS) void pairwise_kernel(
    const float* __restrict__ pred,
    const float* __restrict__ tgt,
    float* __restrict__ partial)
{
    const int b     = blockIdx.x >> 6;    // / CHUNKS
    const int chunk = blockIdx.x & 63;    // % CHUNKS

    const f4* __restrict__ pr[NSRC];
    const f4* __restrict__ tg[NSRC];
#pragma unroll
    for (int s = 0; s < NSRC; ++s) {
        pr[s] = reinterpret_cast<const f4*>(pred + (size_t)(b * NSRC + s) * TF);
        tg[s] = reinterpret_cast<const f4*>(tgt  + (size_t)(b * NSRC + s) * TF);
    }

    const int start = chunk * THREADS + threadIdx.x;   // [0, 16384)

    float acc[NSRC][NSRC];
#pragma unroll
    for (int j = 0; j < NSRC; ++j)
#pragma unroll
        for (int k = 0; k < NSRC; ++k) acc[j][k] = 0.0f;

    // 3 guaranteed strided iterations: issue all 18 loads up-front (MLP),
    // then consume. start + 2*16384 = max 49151 < 64250 always.
    f4 A[3][NSRC], T[3][NSRC];
#pragma unroll
    for (int u = 0; u < 3; ++u) {
        const int i = start + u * STRIDE;
#pragma unroll
        for (int s = 0; s < NSRC; ++s) {
            A[u][s] = __builtin_nontemporal_load(&pr[s][i]);  // pred: NT
            T[u][s] = tg[s][i];                               // tgt: cached
        }
    }
#pragma unroll
    for (int u = 0; u < 3; ++u) {
#pragma unroll
        for (int j = 0; j < NSRC; ++j)
#pragma unroll
            for (int k = 0; k < NSRC; ++k) {
                acc[j][k] += fabsf(A[u][j].x - T[u][k].x)
                           + fabsf(A[u][j].y - T[u][k].y)
                           + fabsf(A[u][j].z - T[u][k].z)
                           + fabsf(A[u][j].w - T[u][k].w);
            }
    }

    // Conditional 4th iteration (start < 64250 - 49152 = 15098).
    const int i3 = start + 3 * STRIDE;
    if (i3 < N4) {
        f4 a[NSRC], t[NSRC];
#pragma unroll
        for (int s = 0; s < NSRC; ++s) {
            a[s] = __builtin_nontemporal_load(&pr[s][i3]);
            t[s] = tg[s][i3];
        }
#pragma unroll
        for (int j = 0; j < NSRC; ++j)
#pragma unroll
            for (int k = 0; k < NSRC; ++k) {
                acc[j][k] += fabsf(a[j].x - t[k].x)
                           + fabsf(a[j].y - t[k].y)
                           + fabsf(a[j].z - t[k].z)
                           + fabsf(a[j].w - t[k].w);
            }
    }

    // Wave shuffle-reduce, cross-wave LDS reduce, one 9-float block store.
    __shared__ float red[THREADS / 64][9];
    const int wave = threadIdx.x >> 6;
    const int lane = threadIdx.x & 63;

#pragma unroll
    for (int j = 0; j < NSRC; ++j)
#pragma unroll
        for (int k = 0; k < NSRC; ++k) {
            float v = acc[j][k];
#pragma unroll
            for (int off = 32; off > 0; off >>= 1) v += __shfl_down(v, off);
            if (lane == 0) red[wave][j * 3 + k] = v;
        }
    __syncthreads();

    if (threadIdx.x < 9) {
        float v = red[0][threadIdx.x] + red[1][threadIdx.x]
                + red[2][threadIdx.x] + red[3][threadIdx.x];
        partial[(size_t)blockIdx.x * 9 + threadIdx.x] = v;
    }
}

// Kernel 2: reduce the 2048x9 partials, per-batch 6-perm argmin, mean.
// out[0] = mean_b min_loss[b]; out[1 + b*3 + s] = (float)best_perm[b][s]
__global__ __launch_bounds__(256) void finalize_kernel(
    const float* __restrict__ partial,
    float* __restrict__ out)
{
    __shared__ float red2[BATCH][8][9];        // 9216 B
    const int t = threadIdx.x;                 // 0..255
    const int b = t >> 3;                      // 0..31
    const int g = t & 7;                       // 0..7 (8 groups of 8 chunks)

    float s[9];
#pragma unroll
    for (int p = 0; p < 9; ++p) s[p] = 0.0f;

    const float* base = partial + (size_t)(b * CHUNKS + g * 8) * 9;
#pragma unroll
    for (int c = 0; c < 8; ++c)
#pragma unroll
        for (int p = 0; p < 9; ++p) s[p] += base[c * 9 + p];

#pragma unroll
    for (int p = 0; p < 9; ++p) red2[b][g][p] = s[p];
    __syncthreads();

    if (t < BATCH) {
        const int bb = t;
        float m[9];
#pragma unroll
        for (int p = 0; p < 9; ++p) {
            float v = 0.0f;
#pragma unroll
            for (int gg = 0; gg < 8; ++gg) v += red2[bb][gg][p];
            m[p] = v * (1.0f / (float)TF);
        }

        const int perms[6][3] = {
            {0,1,2},{0,2,1},{1,0,2},{1,2,0},{2,0,1},{2,1,0}
        };
        float best = 3.402823e38f;
        int   bi   = 0;
#pragma unroll
        for (int p = 0; p < 6; ++p) {
            float l = (m[perms[p][0] * 3 + 0]
                     + m[perms[p][1] * 3 + 1]
                     + m[perms[p][2] * 3 + 2]) * (1.0f / 3.0f);
            if (l < best) { best = l; bi = p; }   // first-occurrence argmin
        }
        out[1 + bb * 3 + 0] = (float)perms[bi][0];
        out[1 + bb * 3 + 1] = (float)perms[bi][1];
        out[1 + bb * 3 + 2] = (float)perms[bi][2];

        // mean of best over lanes 0..31 (single wave)
        float minv = best;
#pragma unroll
        for (int off = 16; off > 0; off >>= 1) minv += __shfl_down(minv, off);
        if (t == 0) out[0] = minv * (1.0f / (float)BATCH);
    }
}

extern "C" void kernel_launch(void* const* d_in, const int* in_sizes, int n_in,
                              void* d_out, int out_size, void* d_ws, size_t ws_size,
                              hipStream_t stream)
{
    const float* pred = (const float*)d_in[0];
    const float* tgt  = (const float*)d_in[1];
    float* out     = (float*)d_out;
    float* partial = (float*)d_ws;   // [2048][9] floats, fully rewritten
                                     // every call (no zeroing needed)

    pairwise_kernel<<<BATCH * CHUNKS, THREADS, 0, stream>>>(pred, tgt, partial);
    finalize_kernel<<<1, 256, 0, stream>>>(partial, out);
}

// Round 6
// 42.201 us; speedup vs baseline: 2.4924x; 1.0225x over previous
//
#include <hip/hip_runtime.h>

// Problem constants (from reference): B=32, S=3, T=1000, F=257
#define BATCH   32
#define NSRC    3
#define TF      257000               // T*F
#define N4      (TF / 4)             // 64250 float4 groups per (b,s) slice
#define CHUNKS  128                  // blocks per batch -> 4096 blocks (2x wave capacity)
#define THREADS 256
#define BLKSPAN (2 * THREADS)        // 512 float4 contiguous per stream per block
#define NBLOCKS (BATCH * CHUNKS)     // 4096

typedef float f4 __attribute__((ext_vector_type(4)));

// Kernel 1: per-block pairwise partial sums.
// Each block reads a CONTIGUOUS 512-float4 (8 KB) range of all 6 streams
// (better DRAM row locality than the old 4x4KB@256KB-stride pattern), with
// 2 iterations/thread. partial[block*9 + j*3 + k] = sum |pred[b,j]-tgt[b,k]|.
__global__ __launch_bounds__(THREADS) void pairwise_kernel(
    const float* __restrict__ pred,
    const float* __restrict__ tgt,
    float* __restrict__ partial)
{
    const int b     = blockIdx.x >> 7;     // / CHUNKS
    const int chunk = blockIdx.x & 127;    // % CHUNKS

    const f4* __restrict__ pr[NSRC];
    const f4* __restrict__ tg[NSRC];
#pragma unroll
    for (int s = 0; s < NSRC; ++s) {
        pr[s] = reinterpret_cast<const f4*>(pred + (size_t)(b * NSRC + s) * TF);
        tg[s] = reinterpret_cast<const f4*>(tgt  + (size_t)(b * NSRC + s) * TF);
    }

    const int i0 = chunk * BLKSPAN + threadIdx.x;   // contiguous block range

    float acc[NSRC][NSRC];
#pragma unroll
    for (int j = 0; j < NSRC; ++j)
#pragma unroll
        for (int k = 0; k < NSRC; ++k) acc[j][k] = 0.0f;

    if (chunk < 125) {
        // Guaranteed both iterations (i1 max = 124*512+511 = 63999 < 64250).
        // Issue all 12 loads up-front; compiler splits to fit VGPR budget.
        f4 A[2][NSRC], T[2][NSRC];
#pragma unroll
        for (int u = 0; u < 2; ++u) {
            const int i = i0 + u * THREADS;
#pragma unroll
            for (int s = 0; s < NSRC; ++s) { A[u][s] = pr[s][i]; T[u][s] = tg[s][i]; }
        }
#pragma unroll
        for (int u = 0; u < 2; ++u)
#pragma unroll
            for (int j = 0; j < NSRC; ++j)
#pragma unroll
                for (int k = 0; k < NSRC; ++k) {
                    acc[j][k] += fabsf(A[u][j].x - T[u][k].x)
                               + fabsf(A[u][j].y - T[u][k].y)
                               + fabsf(A[u][j].z - T[u][k].z)
                               + fabsf(A[u][j].w - T[u][k].w);
                }
    } else {
        // Tail chunks: 125 partial (250 of 512), 126/127 idle (write zeros).
#pragma unroll
        for (int u = 0; u < 2; ++u) {
            const int i = i0 + u * THREADS;
            if (i < N4) {
                f4 a[NSRC], t[NSRC];
#pragma unroll
                for (int s = 0; s < NSRC; ++s) { a[s] = pr[s][i]; t[s] = tg[s][i]; }
#pragma unroll
                for (int j = 0; j < NSRC; ++j)
#pragma unroll
                    for (int k = 0; k < NSRC; ++k) {
                        acc[j][k] += fabsf(a[j].x - t[k].x)
                                   + fabsf(a[j].y - t[k].y)
                                   + fabsf(a[j].z - t[k].z)
                                   + fabsf(a[j].w - t[k].w);
                    }
            }
        }
    }

    // Wave shuffle-reduce, cross-wave LDS reduce, one 9-float block store.
    __shared__ float red[THREADS / 64][9];
    const int wave = threadIdx.x >> 6;
    const int lane = threadIdx.x & 63;

#pragma unroll
    for (int j = 0; j < NSRC; ++j)
#pragma unroll
        for (int k = 0; k < NSRC; ++k) {
            float v = acc[j][k];
#pragma unroll
            for (int off = 32; off > 0; off >>= 1) v += __shfl_down(v, off);
            if (lane == 0) red[wave][j * 3 + k] = v;
        }
    __syncthreads();

    if (threadIdx.x < 9) {
        float v = red[0][threadIdx.x] + red[1][threadIdx.x]
                + red[2][threadIdx.x] + red[3][threadIdx.x];
        partial[(size_t)blockIdx.x * 9 + threadIdx.x] = v;
    }
}

// Kernel 2: reduce the 4096x9 partials, per-batch 6-perm argmin, mean.
// out[0] = mean_b min_loss[b]; out[1 + b*3 + s] = (float)best_perm[b][s]
__global__ __launch_bounds__(256) void finalize_kernel(
    const float* __restrict__ partial,
    float* __restrict__ out)
{
    __shared__ float red2[BATCH][8][9];        // 9216 B
    const int t = threadIdx.x;                 // 0..255
    const int b = t >> 3;                      // 0..31
    const int g = t & 7;                       // 0..7 (8 groups of 16 chunks)

    float s[9];
#pragma unroll
    for (int p = 0; p < 9; ++p) s[p] = 0.0f;

    const float* base = partial + (size_t)(b * CHUNKS + g * 16) * 9;
#pragma unroll
    for (int c = 0; c < 16; ++c)
#pragma unroll
        for (int p = 0; p < 9; ++p) s[p] += base[c * 9 + p];

#pragma unroll
    for (int p = 0; p < 9; ++p) red2[b][g][p] = s[p];
    __syncthreads();

    if (t < BATCH) {
        const int bb = t;
        float m[9];
#pragma unroll
        for (int p = 0; p < 9; ++p) {
            float v = 0.0f;
#pragma unroll
            for (int gg = 0; gg < 8; ++gg) v += red2[bb][gg][p];
            m[p] = v * (1.0f / (float)TF);
        }

        const int perms[6][3] = {
            {0,1,2},{0,2,1},{1,0,2},{1,2,0},{2,0,1},{2,1,0}
        };
        float best = 3.402823e38f;
        int   bi   = 0;
#pragma unroll
        for (int p = 0; p < 6; ++p) {
            float l = (m[perms[p][0] * 3 + 0]
                     + m[perms[p][1] * 3 + 1]
                     + m[perms[p][2] * 3 + 2]) * (1.0f / 3.0f);
            if (l < best) { best = l; bi = p; }   // first-occurrence argmin
        }
        out[1 + bb * 3 + 0] = (float)perms[bi][0];
        out[1 + bb * 3 + 1] = (float)perms[bi][1];
        out[1 + bb * 3 + 2] = (float)perms[bi][2];

        // mean of best over lanes 0..31 (single wave)
        float minv = best;
#pragma unroll
        for (int off = 16; off > 0; off >>= 1) minv += __shfl_down(minv, off);
        if (t == 0) out[0] = minv * (1.0f / (float)BATCH);
    }
}

extern "C" void kernel_launch(void* const* d_in, const int* in_sizes, int n_in,
                              void* d_out, int out_size, void* d_ws, size_t ws_size,
                              hipStream_t stream)
{
    const float* pred = (const float*)d_in[0];
    const float* tgt  = (const float*)d_in[1];
    float* out     = (float*)d_out;
    float* partial = (float*)d_ws;   // [4096][9] floats, fully rewritten
                                     // every call (no zeroing needed)

    pairwise_kernel<<<NBLOCKS, THREADS, 0, stream>>>(pred, tgt, partial);
    finalize_kernel<<<1, 256, 0, stream>>>(partial, out);
}

// Round 7
// 39.164 us; speedup vs baseline: 2.6857x; 1.0775x over previous
//
#include <hip/hip_runtime.h>

// Problem constants (from reference): B=32, S=3, T=1000, F=257
#define BATCH   32
#define NSRC    3
#define TF      257000               // T*F
#define N4      (TF / 4)             // 64250 float4 groups per (b,s) slice
#define CHUNKS  64                   // blocks per batch -> 2048 blocks (1 residency gen)
#define THREADS 256
#define SPAN    (4 * THREADS)        // 1024 float4 contiguous per stream per block
#define NBLOCKS (BATCH * CHUNKS)     // 2048

typedef float f4 __attribute__((ext_vector_type(4)));

// Accumulate one batch of 6 float4 (inline, compile-time indices only --
// NO array-typed helper params: that defeated SROA in R3 and spilled).
#define ACC6(Aj, Tk)                                                      \
    do {                                                                  \
        _Pragma("unroll")                                                 \
        for (int j = 0; j < NSRC; ++j)                                    \
            _Pragma("unroll")                                             \
            for (int k = 0; k < NSRC; ++k) {                              \
                acc[j][k] += fabsf(Aj[j].x - Tk[k].x)                     \
                           + fabsf(Aj[j].y - Tk[k].y)                     \
                           + fabsf(Aj[j].z - Tk[k].z)                     \
                           + fabsf(Aj[j].w - Tk[k].w);                    \
            }                                                             \
    } while (0)

// Kernel 1: per-block pairwise partial sums. Each block reads a CONTIGUOUS
// 1024-float4 (16 KB) range of each of the 6 streams, 4 iterations/thread,
// single full-residency generation (2048 blocks x 4 waves = 8192 waves).
__global__ __launch_bounds__(THREADS) void pairwise_kernel(
    const float* __restrict__ pred,
    const float* __restrict__ tgt,
    float* __restrict__ partial)
{
    const int b     = blockIdx.x >> 6;    // / CHUNKS
    const int chunk = blockIdx.x & 63;    // % CHUNKS

    const f4* __restrict__ pr[NSRC];
    const f4* __restrict__ tg[NSRC];
#pragma unroll
    for (int s = 0; s < NSRC; ++s) {
        pr[s] = reinterpret_cast<const f4*>(pred + (size_t)(b * NSRC + s) * TF);
        tg[s] = reinterpret_cast<const f4*>(tgt  + (size_t)(b * NSRC + s) * TF);
    }

    const int i0 = chunk * SPAN + threadIdx.x;   // contiguous block range

    float acc[NSRC][NSRC];
#pragma unroll
    for (int j = 0; j < NSRC; ++j)
#pragma unroll
        for (int k = 0; k < NSRC; ++k) acc[j][k] = 0.0f;

    if (chunk < 62) {
        // Full 4 iterations guaranteed:
        // max i = 61*1024 + 3*256 + 255 = 63487 < 64250.
        // Two inline 12-load batches (R6-proven shape, VGPR~40, no spill).
        f4 A[2][NSRC], T[2][NSRC];
#pragma unroll
        for (int u = 0; u < 2; ++u) {
            const int i = i0 + u * THREADS;
#pragma unroll
            for (int s = 0; s < NSRC; ++s) { A[u][s] = pr[s][i]; T[u][s] = tg[s][i]; }
        }
        ACC6(A[0], T[0]);
        ACC6(A[1], T[1]);
#pragma unroll
        for (int u = 0; u < 2; ++u) {
            const int i = i0 + (2 + u) * THREADS;
#pragma unroll
            for (int s = 0; s < NSRC; ++s) { A[u][s] = pr[s][i]; T[u][s] = tg[s][i]; }
        }
        ACC6(A[0], T[0]);
        ACC6(A[1], T[1]);
    } else {
        // Tail: chunk 62 partial (63488..64249), chunk 63 idle (zeros).
#pragma unroll
        for (int u = 0; u < 4; ++u) {
            const int i = i0 + u * THREADS;
            if (i < N4) {
                f4 a[NSRC], t[NSRC];
#pragma unroll
                for (int s = 0; s < NSRC; ++s) { a[s] = pr[s][i]; t[s] = tg[s][i]; }
                ACC6(a, t);
            }
        }
    }

    // Wave shuffle-reduce, cross-wave LDS reduce, one 9-float block store.
    __shared__ float red[THREADS / 64][9];
    const int wave = threadIdx.x >> 6;
    const int lane = threadIdx.x & 63;

#pragma unroll
    for (int j = 0; j < NSRC; ++j)
#pragma unroll
        for (int k = 0; k < NSRC; ++k) {
            float v = acc[j][k];
#pragma unroll
            for (int off = 32; off > 0; off >>= 1) v += __shfl_down(v, off);
            if (lane == 0) red[wave][j * 3 + k] = v;
        }
    __syncthreads();

    if (threadIdx.x < 9) {
        float v = red[0][threadIdx.x] + red[1][threadIdx.x]
                + red[2][threadIdx.x] + red[3][threadIdx.x];
        partial[(size_t)blockIdx.x * 9 + threadIdx.x] = v;
    }
}

// Kernel 2: reduce the 2048x9 partials, per-batch 6-perm argmin, mean.
// out[0] = mean_b min_loss[b]; out[1 + b*3 + s] = (float)best_perm[b][s]
__global__ __launch_bounds__(256) void finalize_kernel(
    const float* __restrict__ partial,
    float* __restrict__ out)
{
    __shared__ float red2[BATCH][8][9];        // 9216 B
    const int t = threadIdx.x;                 // 0..255
    const int b = t >> 3;                      // 0..31
    const int g = t & 7;                       // 0..7 (8 groups of 8 chunks)

    float s[9];
#pragma unroll
    for (int p = 0; p < 9; ++p) s[p] = 0.0f;

    const float* base = partial + (size_t)(b * CHUNKS + g * 8) * 9;
#pragma unroll
    for (int c = 0; c < 8; ++c)
#pragma unroll
        for (int p = 0; p < 9; ++p) s[p] += base[c * 9 + p];

#pragma unroll
    for (int p = 0; p < 9; ++p) red2[b][g][p] = s[p];
    __syncthreads();

    if (t < BATCH) {
        const int bb = t;
        float m[9];
#pragma unroll
        for (int p = 0; p < 9; ++p) {
            float v = 0.0f;
#pragma unroll
            for (int gg = 0; gg < 8; ++gg) v += red2[bb][gg][p];
            m[p] = v * (1.0f / (float)TF);
        }

        const int perms[6][3] = {
            {0,1,2},{0,2,1},{1,0,2},{1,2,0},{2,0,1},{2,1,0}
        };
        float best = 3.402823e38f;
        int   bi   = 0;
#pragma unroll
        for (int p = 0; p < 6; ++p) {
            float l = (m[perms[p][0] * 3 + 0]
                     + m[perms[p][1] * 3 + 1]
                     + m[perms[p][2] * 3 + 2]) * (1.0f / 3.0f);
            if (l < best) { best = l; bi = p; }   // first-occurrence argmin
        }
        out[1 + bb * 3 + 0] = (float)perms[bi][0];
        out[1 + bb * 3 + 1] = (float)perms[bi][1];
        out[1 + bb * 3 + 2] = (float)perms[bi][2];

        // mean of best over lanes 0..31 (single wave)
        float minv = best;
#pragma unroll
        for (int off = 16; off > 0; off >>= 1) minv += __shfl_down(minv, off);
        if (t == 0) out[0] = minv * (1.0f / (float)BATCH);
    }
}

extern "C" void kernel_launch(void* const* d_in, const int* in_sizes, int n_in,
                              void* d_out, int out_size, void* d_ws, size_t ws_size,
                              hipStream_t stream)
{
    const float* pred = (const float*)d_in[0];
    const float* tgt  = (const float*)d_in[1];
    float* out     = (float*)d_out;
    float* partial = (float*)d_ws;   // [2048][9] floats, fully rewritten
                                     // every call (no zeroing needed)

    pairwise_kernel<<<NBLOCKS, THREADS, 0, stream>>>(pred, tgt, partial);
    finalize_kernel<<<1, 256, 0, stream>>>(partial, out);
}